// Round 15
// baseline (140.769 us; speedup 1.0000x reference)
//
#include <hip/hip_runtime.h>

// ---------- types / helpers ----------
typedef __attribute__((ext_vector_type(4))) float f32x4;
typedef __attribute__((ext_vector_type(8))) _Float16 f16x8;
typedef __attribute__((ext_vector_type(4))) _Float16 f16x4;
typedef __attribute__((ext_vector_type(2))) _Float16 f16x2;

#define MFMA_F16(a, b, c) __builtin_amdgcn_mfma_f32_16x16x32_f16(a, b, c, 0, 0, 0)

__device__ __forceinline__ void gload_lds16(const void* g, void* l) {
  // async global->LDS, 16B/lane; LDS dest is wave-uniform base + lane*16
  __builtin_amdgcn_global_load_lds(
      (const __attribute__((address_space(1))) void*)g,
      (__attribute__((address_space(3))) void*)l, 16, 0, 0);
}
__device__ __forceinline__ f16x2 pk2(float a, float b) {
  return __builtin_bit_cast(f16x2, __builtin_amdgcn_cvt_pkrtz(a, b));
}
// counted-vmcnt pipeline barriers
__device__ __forceinline__ void pipe_barrier_v4() {
  asm volatile("s_waitcnt vmcnt(4) lgkmcnt(0)" ::: "memory");
  __builtin_amdgcn_sched_barrier(0);
  __builtin_amdgcn_s_barrier();
}
__device__ __forceinline__ void pipe_barrier_v3() {
  asm volatile("s_waitcnt vmcnt(3) lgkmcnt(0)" ::: "memory");
  __builtin_amdgcn_sched_barrier(0);
  __builtin_amdgcn_s_barrier();
}
__device__ __forceinline__ void pipe_barrier_v2() {
  asm volatile("s_waitcnt vmcnt(2) lgkmcnt(0)" ::: "memory");
  __builtin_amdgcn_sched_barrier(0);
  __builtin_amdgcn_s_barrier();
}
__device__ __forceinline__ void pipe_barrier_v0() {
  asm volatile("s_waitcnt vmcnt(0) lgkmcnt(0)" ::: "memory");
  __builtin_amdgcn_sched_barrier(0);
  __builtin_amdgcn_s_barrier();
}

// ---------- prep: transpose Wqkv, Wproj -> f16 (x-cast fused into qkv GEMM) --
// blocks [0,3072): Wqkv^T; [3072,4096): Wproj^T
__global__ __launch_bounds__(256) void prep_kernel(
    const float* __restrict__ Wqkv, _Float16* __restrict__ wqt,
    const float* __restrict__ Wproj, _Float16* __restrict__ wpt) {
  __shared__ float tile[32][33];
  const int bx = blockIdx.x;
  const float* W;
  _Float16* wt;
  int N, n0, k0;
  if (bx < 3072) {
    W = Wqkv; wt = wqt; N = 3072;
    n0 = (bx % 96) * 32; k0 = (bx / 96) * 32;
  } else {
    const int t = bx - 3072;
    W = Wproj; wt = wpt; N = 1024;
    n0 = (t % 32) * 32; k0 = (t / 32) * 32;
  }
  const int tx = threadIdx.x & 31, ty = threadIdx.x >> 5;  // 32x8
#pragma unroll
  for (int j = 0; j < 32; j += 8)
    tile[ty + j][tx] = W[(size_t)(k0 + ty + j) * N + n0 + tx];
  __syncthreads();
#pragma unroll
  for (int j = 0; j < 32; j += 8)
    wt[(size_t)(n0 + ty + j) * 1024 + k0 + tx] = (_Float16)tile[tx][ty + j];
}

// ---------- GEMM: qkv = x @ Wqkv + b (x read as f32, reg-staged -> f16 LDS),
// 3-buf counted-vmcnt pipe, XCD swizzle ----------
__global__ __launch_bounds__(256) void gemm_qkv_kernel(
    const float* __restrict__ x, const _Float16* __restrict__ wt,
    const float* __restrict__ bias, _Float16* __restrict__ QF,
    _Float16* __restrict__ KF, _Float16* __restrict__ KT,
    _Float16* __restrict__ VT) {
  __shared__ __attribute__((aligned(16))) _Float16 lg[24576];
  const int tid = threadIdx.x, lane = tid & 63, w = tid >> 6;
  const int wg = blockIdx.x;
  const int cx = wg & 7, c = wg >> 3;  // c in [0,96)
  const int bxl = (cx & 1) * 12 + c % 12;   // 0..23
  const int byl = (cx >> 1) * 8 + c / 12;   // 0..31
  const int m0 = byl * 128, n0 = bxl * 128;
  const int wr = (w >> 1) * 64, wc = (w & 1) * 64;
  f32x4 acc[4][4] = {};

  const int srow = lane >> 2;
  const int scol = (((lane & 3) ^ ((lane >> 3) & 3)) * 8);
  const int fr = lane & 15, fg = lane >> 4;
  const int rswz = (fr >> 1) & 3;

  // A: load x (f32) into regs; written to LDS (RNE f16) after compute phase
  auto a_load = [&](int k0, f32x4 (&ar)[4]) {
#pragma unroll
    for (int j = 0; j < 2; ++j) {
      const int r = 32 * w + 16 * j + srow;
      const float* src = x + (size_t)(m0 + r) * 1024 + k0 + scol;
      ar[2 * j] = *(const f32x4*)src;
      ar[2 * j + 1] = *(const f32x4*)(src + 4);
    }
  };
  auto a_write = [&](int buf, const f32x4 (&ar)[4]) {
#pragma unroll
    for (int j = 0; j < 2; ++j) {
      f16x8 h;
#pragma unroll
      for (int q = 0; q < 4; ++q) {
        h[q] = (_Float16)ar[2 * j][q];          // RNE
        h[4 + q] = (_Float16)ar[2 * j + 1][q];
      }
      *(f16x8*)&lg[buf * 8192 + (32 * w + 16 * j) * 32 + lane * 8] = h;
    }
  };
  auto b_stage = [&](int buf, int k0) {
#pragma unroll
    for (int j = 0; j < 2; ++j) {
      const int rbase = 32 * w + 16 * j;
      const int r = rbase + srow;
      gload_lds16(wt + (size_t)(n0 + r) * 1024 + k0 + scol,
                  &lg[buf * 8192 + 4096 + rbase * 32]);
    }
  };
  auto mfma_step = [&](int ab) {
    f16x8 af[4], bfr[4];
#pragma unroll
    for (int m = 0; m < 4; ++m)
      af[m] = *(const f16x8*)&lg[ab + (wr + 16 * m + fr) * 32 + ((fg ^ rswz) * 8)];
#pragma unroll
    for (int n = 0; n < 4; ++n)
      bfr[n] = *(const f16x8*)&lg[ab + 4096 + (wc + 16 * n + fr) * 32 + ((fg ^ rswz) * 8)];
#pragma unroll
    for (int m = 0; m < 4; ++m)
#pragma unroll
      for (int n = 0; n < 4; ++n) acc[m][n] = MFMA_F16(af[m], bfr[n], acc[m][n]);
  };

  // prologue: tiles 0,1 (A via regs, B via gload); B1 stays in flight
  {
    f32x4 arA[4], arB[4];
    a_load(0, arA);
    b_stage(0, 0);
    a_load(32, arB);
    b_stage(1, 32);
    a_write(0, arA);
    a_write(1, arB);
    pipe_barrier_v2();
  }
  for (int T = 0; T < 30; T += 3) {
#pragma unroll
    for (int s = 0; s < 3; ++s) {   // s == t%3 == cur (compile-time)
      f32x4 ar[4];
      a_load((T + s + 2) * 32, ar);
      b_stage((s + 2) % 3, (T + s + 2) * 32);
      mfma_step(s * 8192);
      a_write((s + 2) % 3, ar);   // implicit vmcnt wait drains ar + older B
      pipe_barrier_v2();
    }
  }
  mfma_step(0);        // t=30
  pipe_barrier_v0();
  mfma_step(8192);     // t=31
  pipe_barrier_v0();

  const int fq = fg * 4;
#pragma unroll
  for (int n = 0; n < 4; ++n) {
    const float bv = bias[n0 + wc + 16 * n + fr];
#pragma unroll
    for (int m = 0; m < 4; ++m)
#pragma unroll
      for (int i = 0; i < 4; ++i)
        lg[(wr + 16 * m + fq + i) * 129 + wc + 16 * n + fr] =
            (_Float16)(acc[m][n][i] + bv);
  }
  __syncthreads();
  const int b = m0 >> 11, nnb = m0 & 2047;
  const int h0 = 2 * (bxl & 7);
  const int sPhase = bxl >> 3;  // 0=Q 1=K 2=V (uniform per block)
  if (sPhase <= 1) {
    _Float16* __restrict__ dst = (sPhase == 0) ? QF : KF;
#pragma unroll
    for (int p = 0; p < 8; ++p) {
      const int r = p * 16 + (tid >> 4);
      const int cc = tid & 15;
      f16x8 vals;
#pragma unroll
      for (int j = 0; j < 8; ++j) vals[j] = lg[r * 129 + cc * 8 + j];
      const int h = cc >> 3, d = (cc & 7) * 8;
      *(f16x8*)&dst[((size_t)((b * 16 + h0 + h) * 2048 + nnb + r)) * 64 + d] = vals;
    }
  }
  if (sPhase >= 1) {
    _Float16* __restrict__ T = (sPhase == 1) ? KT : VT;
#pragma unroll
    for (int p = 0; p < 8; ++p) {
      const int lr = p * 16 + (tid >> 4);
      const int cc = tid & 15;
      f16x8 vals;
#pragma unroll
      for (int j = 0; j < 8; ++j) vals[j] = lg[(cc * 8 + j) * 129 + lr];
      const int h = lr >> 6, d = lr & 63;
      *(f16x8*)&T[((size_t)((b * 16 + h0 + h) * 64 + d)) * 2048 + nnb + cc * 8] = vals;
    }
  }
}

// ---------- Gram partial: 256 WGs, each 256 keys of one head (f32 out) ------
__global__ __launch_bounds__(256) void gram_partial_kernel(
    const _Float16* __restrict__ KT, float* __restrict__ GP) {
  __shared__ __attribute__((aligned(16))) _Float16 sT[3][4096];
  const int tid = threadIdx.x, lane = tid & 63, w = tid >> 6;
  const int bh = blockIdx.x >> 3, qt = blockIdx.x & 7;
  const _Float16* src = KT + (size_t)bh * 64 * 2048 + qt * 256;
  const int s_r = lane >> 3, s_cg = lane & 7;
  const int fr = lane & 15, fg = lane >> 4;
  const int kswz = fr & 7;

  auto stage = [&](int buf, int n0) {
#pragma unroll
    for (int j = 0; j < 2; ++j) {
      const int rbase = 8 * w + 32 * j;
      gload_lds16(src + (size_t)(rbase + s_r) * 2048 + n0 + ((s_cg ^ s_r) * 8),
                  &sT[buf][rbase * 64]);
    }
  };
  f32x4 acc[4] = {};
  auto mm = [&](int buf) {
    f16x8 af[2];
#pragma unroll
    for (int ks = 0; ks < 2; ++ks)
      af[ks] = *(const f16x8*)&sT[buf][(16 * w + fr) * 64 + (((ks * 4 + fg) ^ kswz) * 8)];
#pragma unroll
    for (int nt = 0; nt < 4; ++nt)
#pragma unroll
      for (int ks = 0; ks < 2; ++ks)
        acc[nt] = MFMA_F16(
            af[ks],
            *(const f16x8*)&sT[buf][(16 * nt + fr) * 64 + (((ks * 4 + fg) ^ kswz) * 8)],
            acc[nt]);
  };

  stage(0, 0);
  stage(1, 64);
  pipe_barrier_v2();
  stage(2, 128); mm(0); pipe_barrier_v2();
  stage(0, 192); mm(1); pipe_barrier_v2();
  mm(2); pipe_barrier_v0();
  mm(0);

  float* dst = GP + (size_t)blockIdx.x * 4096;
#pragma unroll
  for (int nt = 0; nt < 4; ++nt)
#pragma unroll
    for (int i = 0; i < 4; ++i)
      dst[(16 * w + fg * 4 + i) * 64 + 16 * nt + fr] = acc[nt][i];
}

// ---------- Gram reduce: sum 8 partials -> split f16 hi/lo ----------
__global__ __launch_bounds__(256) void gram_reduce_kernel(
    const float* __restrict__ GP, _Float16* __restrict__ GH,
    _Float16* __restrict__ GL) {
  const int bh = blockIdx.x >> 2, seg = blockIdx.x & 3;
  const int e0 = seg * 1024 + threadIdx.x * 4;
  const float* p = GP + (size_t)bh * 8 * 4096 + e0;
  f32x4 s = *(const f32x4*)p;
#pragma unroll
  for (int o = 1; o < 8; ++o) s += *(const f32x4*)(p + o * 4096);
  f16x4 gh, gl;
#pragma unroll
  for (int j = 0; j < 4; ++j) {
    gh[j] = (_Float16)s[j];
    gl[j] = (_Float16)(s[j] - (float)gh[j]);
  }
  *(f16x4*)&GH[(size_t)bh * 4096 + e0] = gh;
  *(f16x4*)&GL[(size_t)bh * 4096 + e0] = gl;
}

// ---------- attention: 128 q-rows/WG; swapped QK^T, P in registers,
// 4-buf stage-3-ahead counted-vmcnt pipeline + cross-tile overlap.
// minvl2 pre-folded into Q fragments; lsum via ones-MFMA. (identical to r14)
// LDS (f16 idx): K bufs @ b*4096 (b=0..3) | VT bufs @ 16384 + b*4096. 64KB.
__global__ __launch_bounds__(256) void attn_kernel(
    const _Float16* __restrict__ QF, const _Float16* __restrict__ KF,
    const _Float16* __restrict__ VT, const _Float16* __restrict__ GH,
    const _Float16* __restrict__ GL, _Float16* __restrict__ OB,
    const float* __restrict__ sigma_p, const float* __restrict__ gamma_p) {
  __shared__ __attribute__((aligned(16))) _Float16 lds[32768];

  const int tid = threadIdx.x, lane = tid & 63, w = tid >> 6;
  const int wg = blockIdx.x;
  const int c = wg >> 3;                  // 0..63
  const int bh = (wg & 7) * 4 + (c >> 4); // b*16 + h
  const int q0 = (c & 15) * 128;
  const size_t base = (size_t)bh * (2048 * 64);
  const float sigma = sigma_p[0], gamma = gamma_p[0];
  const int fr = lane & 15, fg = lane >> 4;
  const int s_r = lane >> 3, s_cg = lane & 7;
  const int kswz = fr & 7;

  const _Float16* Kbh = KF + base;
  const _Float16* Tbh = VT + base;  // [64 d][2048 n]

  f16x8 qf[2][2];
#pragma unroll
  for (int m = 0; m < 2; ++m)
#pragma unroll
    for (int ks = 0; ks < 2; ++ks)
      qf[m][ks] = *(const f16x8*)(QF + base +
                                  (size_t)(q0 + 32 * w + 16 * m + fr) * 64 +
                                  ks * 32 + fg * 8);

  auto stage64 = [&](int dstoff, const _Float16* g, int srcstride) {
#pragma unroll
    for (int j = 0; j < 2; ++j) {
      const int rbase = 8 * w + 32 * j;
      gload_lds16(g + (size_t)(rbase + s_r) * srcstride + ((s_cg ^ s_r) * 8),
                  &lds[dstoff + rbase * 64]);
    }
  };
  auto stage64K = [&](int dstoff, const _Float16* g) {
#pragma unroll
    for (int j = 0; j < 2; ++j) {
      const int rbase = 8 * w + 32 * j;
      const int r = rbase + s_r;
      const int pr = (r & 0x23) | ((r & 0x0C) << 1) | ((r & 0x10) >> 2);
      gload_lds16(g + (size_t)pr * 64 + ((s_cg ^ s_r) * 8),
                  &lds[dstoff + rbase * 64]);
    }
  };
  auto stage_tile = [&](int b, int kb) {
    stage64K(b * 4096, Kbh + (size_t)kb * 4096);
    stage64(16384 + b * 4096, Tbh + kb * 64, 2048);
  };

  // ---- prologue: minvl2 from q^T G q ----
  stage64(0, GH + (size_t)bh * 4096, 64);
  stage64(4096, GL + (size_t)bh * 4096, 64);
  __syncthreads();
  float minvl2[2];
  float* Yp = (float*)&lds[8192 + w * 2048];
#pragma unroll
  for (int m = 0; m < 2; ++m) {
    f32x4 yacc[4] = {};
#pragma unroll
    for (int nt = 0; nt < 4; ++nt) {
#pragma unroll
      for (int ks = 0; ks < 2; ++ks) {
        const int off = (16 * nt + fr) * 64 + (((ks * 4 + fg) ^ kswz) * 8);
        yacc[nt] = MFMA_F16(qf[m][ks], *(const f16x8*)&lds[off], yacc[nt]);
        yacc[nt] = MFMA_F16(qf[m][ks], *(const f16x8*)&lds[4096 + off], yacc[nt]);
      }
    }
#pragma unroll
    for (int nt = 0; nt < 4; ++nt)
#pragma unroll
      for (int i = 0; i < 4; ++i) Yp[(fg * 4 + i) * 64 + 16 * nt + fr] = yacc[nt][i];
    float zp = 0.0f;
#pragma unroll
    for (int ks = 0; ks < 2; ++ks) {
      const f32x4 y0 = *(const f32x4*)&Yp[fr * 64 + ks * 32 + fg * 8];
      const f32x4 y1 = *(const f32x4*)&Yp[fr * 64 + ks * 32 + fg * 8 + 4];
#pragma unroll
      for (int cc = 0; cc < 4; ++cc) {
        zp += y0[cc] * (float)qf[m][ks][cc];
        zp += y1[cc] * (float)qf[m][ks][cc + 4];
      }
    }
    zp += __shfl_xor(zp, 16);
    zp += __shfl_xor(zp, 32);
    const float rms = sqrtf(fmaxf(zp, 0.0f)) * (1.0f / 362.038672f);
    minvl2[m] = gamma / (sigma + rms) * 0.125f * 1.44269504f;  // fold log2(e)
  }
#pragma unroll
  for (int m = 0; m < 2; ++m)
#pragma unroll
    for (int ks = 0; ks < 2; ++ks) {
      f16x8 q = qf[m][ks], r;
#pragma unroll
      for (int j = 0; j < 4; ++j) {
        const f16x2 t = pk2((float)q[2 * j] * minvl2[m],
                            (float)q[2 * j + 1] * minvl2[m]);
        r[2 * j] = t[0];
        r[2 * j + 1] = t[1];
      }
      qf[m][ks] = r;
    }
  __syncthreads();

  f32x4 oacc[2][4] = {};
  f32x4 lacc[2] = {};
  f16x8 ones;
#pragma unroll
  for (int j = 0; j < 8; ++j) ones[j] = (_Float16)1.0f;

  auto qk_tile = [&](int kbuf, f32x4 (&pn)[2][4]) {
#pragma unroll
    for (int n = 0; n < 4; ++n) {
      const int offb = kbuf * 4096 + (16 * n + fr) * 64;
      const f16x8 kf0 = *(const f16x8*)&lds[offb + ((fg ^ kswz) * 8)];
      const f16x8 kf1 = *(const f16x8*)&lds[offb + (((4 + fg) ^ kswz) * 8)];
#pragma unroll
      for (int m = 0; m < 2; ++m) {
        f32x4 a = {};
        a = MFMA_F16(kf0, qf[m][0], a);
        a = MFMA_F16(kf1, qf[m][1], a);
        pn[m][n] = a;
      }
    }
  };
  auto exp_pack = [&](f32x4 (&pn)[2][4], f16x8 (&pa)[2][2]) {
#pragma unroll
    for (int m = 0; m < 2; ++m) {
#pragma unroll
      for (int n = 0; n < 4; ++n)
#pragma unroll
        for (int i = 0; i < 4; ++i)
          pn[m][n][i] = __builtin_amdgcn_exp2f(pn[m][n][i]);
#pragma unroll
      for (int k2 = 0; k2 < 2; ++k2) {
        const f16x2 c0 = pk2(pn[m][2 * k2][0], pn[m][2 * k2][1]);
        const f16x2 c1 = pk2(pn[m][2 * k2][2], pn[m][2 * k2][3]);
        const f16x2 c2 = pk2(pn[m][2 * k2 + 1][0], pn[m][2 * k2 + 1][1]);
        const f16x2 c3 = pk2(pn[m][2 * k2 + 1][2], pn[m][2 * k2 + 1][3]);
        pa[m][k2][0] = c0[0]; pa[m][k2][1] = c0[1];
        pa[m][k2][2] = c1[0]; pa[m][k2][3] = c1[1];
        pa[m][k2][4] = c2[0]; pa[m][k2][5] = c2[1];
        pa[m][k2][6] = c3[0]; pa[m][k2][7] = c3[1];
      }
    }
  };
  auto pv_tile = [&](int vbuf, f16x8 (&pa)[2][2]) {
#pragma unroll
    for (int k2 = 0; k2 < 2; ++k2) {
#pragma unroll
      for (int nf = 0; nf < 4; ++nf) {
        const int off = 16384 + vbuf * 4096 + (16 * nf + fr) * 64 +
                        (((k2 * 4 + fg) ^ kswz) * 8);
        const f16x8 vt = *(const f16x8*)&lds[off];
        oacc[0][nf] = MFMA_F16(vt, pa[0][k2], oacc[0][nf]);
        oacc[1][nf] = MFMA_F16(vt, pa[1][k2], oacc[1][nf]);
      }
      lacc[0] = MFMA_F16(ones, pa[0][k2], lacc[0]);
      lacc[1] = MFMA_F16(ones, pa[1][k2], lacc[1]);
    }
  };

  f32x4 pn[2][4];
  f16x8 pa[2][2][2];  // [ping][m][k2]

  stage_tile(0, 0);
  stage_tile(1, 1);
  stage_tile(2, 2);
  pipe_barrier_v4();
  qk_tile(0, pn);
  exp_pack(pn, pa[0]);

  for (int T = 0; T < 28; T += 4) {
#pragma unroll
    for (int s = 0; s < 4; ++s) {   // t = T+s ; t&3 == s
      stage_tile((s + 3) & 3, T + s + 3);
      __builtin_amdgcn_s_setprio(1);
      qk_tile((s + 1) & 3, pn);
      __builtin_amdgcn_s_setprio(0);
      __builtin_amdgcn_s_setprio(1);
      pv_tile(s & 3, pa[s & 1]);
      __builtin_amdgcn_s_setprio(0);
      exp_pack(pn, pa[(s + 1) & 1]);
      pipe_barrier_v4();
    }
  }
  {
    stage_tile(3, 31);
    __builtin_amdgcn_s_setprio(1); qk_tile(1, pn); __builtin_amdgcn_s_setprio(0);
    __builtin_amdgcn_s_setprio(1); pv_tile(0, pa[0]); __builtin_amdgcn_s_setprio(0);
    exp_pack(pn, pa[1]);
    pipe_barrier_v4();
    __builtin_amdgcn_s_setprio(1); qk_tile(2, pn); __builtin_amdgcn_s_setprio(0);
    __builtin_amdgcn_s_setprio(1); pv_tile(1, pa[1]); __builtin_amdgcn_s_setprio(0);
    exp_pack(pn, pa[0]);
    pipe_barrier_v0();
    __builtin_amdgcn_s_setprio(1); qk_tile(3, pn); __builtin_amdgcn_s_setprio(0);
    __builtin_amdgcn_s_setprio(1); pv_tile(2, pa[0]); __builtin_amdgcn_s_setprio(0);
    exp_pack(pn, pa[1]);
    pipe_barrier_v0();
    __builtin_amdgcn_s_setprio(1); pv_tile(3, pa[1]); __builtin_amdgcn_s_setprio(0);
  }

  float inv[2];
#pragma unroll
  for (int m = 0; m < 2; ++m) inv[m] = 1.0f / lacc[m][0];

  const int b = bh >> 4, h = bh & 15;
#pragma unroll
  for (int m = 0; m < 2; ++m) {
    const size_t orow = (size_t)(b * 2048 + q0 + 32 * w + 16 * m + fr);
#pragma unroll
    for (int nf = 0; nf < 4; ++nf) {
      f16x4 ov;
#pragma unroll
      for (int i = 0; i < 4; ++i) ov[i] = (_Float16)(oacc[m][nf][i] * inv[m]);
      *(f16x4*)&OB[orow * 1024 + h * 64 + 16 * nf + 4 * fg] = ov;
    }
  }
}

// ---------- GEMM: out = O @ Wproj + b, f32 out, BM=64 tiles, 3-buf pipe ------
__global__ __launch_bounds__(256) void gemm_proj_kernel(
    const _Float16* __restrict__ A, const _Float16* __restrict__ Bt,
    const float* __restrict__ bias, float* __restrict__ out) {
  __shared__ __attribute__((aligned(16))) _Float16 lg[18432];
  const int tid = threadIdx.x, lane = tid & 63, w = tid >> 6;
  const int wg = blockIdx.x;
  const int c = wg >> 3;                       // 0..63
  const int bxl = c & 7;                       // 0..7
  const int byl = (wg & 7) * 8 + (c >> 3);     // 0..63
  const int m0 = byl * 64, n0 = bxl * 128;
  const int wr = (w >> 1) * 32, wc = (w & 1) * 64;
  f32x4 acc[2][4] = {};
  const int srow = lane >> 2;
  const int scol = (((lane & 3) ^ ((lane >> 3) & 3)) * 8);
  const int fr = lane & 15, fg = lane >> 4;
  const int rswz = (fr >> 1) & 3;

  auto stageT = [&](int buf, int k0) {
    {
      const int rbase = 16 * w;
      gload_lds16(A + (size_t)(m0 + rbase + srow) * 1024 + k0 + scol,
                  &lg[buf * 6144 + rbase * 32]);
    }
#pragma unroll
    for (int j = 0; j < 2; ++j) {
      const int rbase = 32 * w + 16 * j;
      gload_lds16(Bt + (size_t)(n0 + rbase + srow) * 1024 + k0 + scol,
                  &lg[buf * 6144 + 2048 + rbase * 32]);
    }
  };
  auto mfma_step = [&](int ab) {
    f16x8 af[2], bfr[4];
#pragma unroll
    for (int m = 0; m < 2; ++m)
      af[m] = *(const f16x8*)&lg[ab + (wr + 16 * m + fr) * 32 + ((fg ^ rswz) * 8)];
#pragma unroll
    for (int n = 0; n < 4; ++n)
      bfr[n] = *(const f16x8*)&lg[ab + 2048 + (wc + 16 * n + fr) * 32 + ((fg ^ rswz) * 8)];
#pragma unroll
    for (int m = 0; m < 2; ++m)
#pragma unroll
      for (int n = 0; n < 4; ++n) acc[m][n] = MFMA_F16(af[m], bfr[n], acc[m][n]);
  };

  stageT(0, 0);
  stageT(1, 32);
  pipe_barrier_v3();
  for (int T = 0; T < 30; T += 3) {
#pragma unroll
    for (int s = 0; s < 3; ++s) {
      stageT((s + 2) % 3, (T + s + 2) * 32);
      mfma_step(s * 6144);
      pipe_barrier_v3();
    }
  }
  mfma_step(0);       // t=30
  pipe_barrier_v0();
  mfma_step(6144);    // t=31
  pipe_barrier_v0();

  const int fq = fg * 4;
#pragma unroll
  for (int n = 0; n < 4; ++n) {
    const int col = n0 + wc + 16 * n + fr;
    const float bv = bias[col];
#pragma unroll
    for (int m = 0; m < 2; ++m) {
#pragma unroll
      for (int i = 0; i < 4; ++i) {
        const int row = m0 + wr + 16 * m + fq + i;
        out[(size_t)row * 1024 + col] = acc[m][n][i] + bv;
      }
    }
  }
}

// ---------- launch ----------
extern "C" void kernel_launch(void* const* d_in, const int* in_sizes, int n_in,
                              void* d_out, int out_size, void* d_ws, size_t ws_size,
                              hipStream_t stream) {
  const float* x = (const float*)d_in[0];
  const float* Wqkv = (const float*)d_in[1];
  const float* bqkv = (const float*)d_in[2];
  const float* Wproj = (const float*)d_in[3];
  const float* bproj = (const float*)d_in[4];
  const float* sigma = (const float*)d_in[5];
  const float* gamma = (const float*)d_in[6];
  float* out = (float*)d_out;

  char* ws = (char*)d_ws;
  const size_t MB = 1024 * 1024;
  _Float16* WQT = (_Float16*)(ws + 8 * MB);   // 6MB  Wqkv^T (dead after qkv GEMM)
  _Float16* WPT = (_Float16*)(ws + 14 * MB);  // 2MB  Wproj^T
  _Float16* QF  = (_Float16*)(ws + 16 * MB);  // 8MB  [B,H,N,D]
  _Float16* KF  = (_Float16*)(ws + 24 * MB);  // 8MB  [B,H,N,D]
  _Float16* VT  = (_Float16*)(ws + 32 * MB);  // 8MB  [B,H,D,N]
  _Float16* KT  = (_Float16*)(ws + 40 * MB);  // 8MB  (dead after gram)
  _Float16* OB  = (_Float16*)(ws + 40 * MB);  // 8MB  attn out (over KT)
  _Float16* GH  = (_Float16*)(ws + 8 * MB);   // 256KB Gram hi (over dead WQT)
  _Float16* GL  = (_Float16*)(ws + 8 * MB + 512 * 1024);  // 256KB Gram lo
  float*    GP  = (float*)(ws + 9 * MB);      // 4MB  Gram partials (f32, 256x4096)

  prep_kernel<<<4096, 256, 0, stream>>>(Wqkv, WQT, Wproj, WPT);
  gemm_qkv_kernel<<<768, 256, 0, stream>>>(x, WQT, bqkv, QF, KF, KT, VT);
  gram_partial_kernel<<<256, 256, 0, stream>>>(KT, GP);
  gram_reduce_kernel<<<128, 256, 0, stream>>>(GP, GH, GL);
  attn_kernel<<<512, 256, 0, stream>>>(QF, KF, VT, GH, GL, OB, sigma, gamma);
  gemm_proj_kernel<<<512, 256, 0, stream>>>(OB, WPT, bproj, out);
}

// Round 16
// 116.452 us; speedup vs baseline: 1.2088x; 1.2088x over previous
//
#include <hip/hip_runtime.h>

// ---------- types / helpers ----------
typedef __attribute__((ext_vector_type(4))) float f32x4;
typedef __attribute__((ext_vector_type(8))) _Float16 f16x8;
typedef __attribute__((ext_vector_type(4))) _Float16 f16x4;
typedef __attribute__((ext_vector_type(2))) _Float16 f16x2;

#define MFMA_F16(a, b, c) __builtin_amdgcn_mfma_f32_16x16x32_f16(a, b, c, 0, 0, 0)

__device__ __forceinline__ void gload_lds16(const void* g, void* l) {
  // async global->LDS, 16B/lane; LDS dest is wave-uniform base + lane*16
  __builtin_amdgcn_global_load_lds(
      (const __attribute__((address_space(1))) void*)g,
      (__attribute__((address_space(3))) void*)l, 16, 0, 0);
}
__device__ __forceinline__ f16x2 pk2(float a, float b) {
  return __builtin_bit_cast(f16x2, __builtin_amdgcn_cvt_pkrtz(a, b));
}
// counted-vmcnt pipeline barriers
__device__ __forceinline__ void pipe_barrier_v4() {
  asm volatile("s_waitcnt vmcnt(4) lgkmcnt(0)" ::: "memory");
  __builtin_amdgcn_sched_barrier(0);
  __builtin_amdgcn_s_barrier();
}
__device__ __forceinline__ void pipe_barrier_v3() {
  asm volatile("s_waitcnt vmcnt(3) lgkmcnt(0)" ::: "memory");
  __builtin_amdgcn_sched_barrier(0);
  __builtin_amdgcn_s_barrier();
}
__device__ __forceinline__ void pipe_barrier_v2() {
  asm volatile("s_waitcnt vmcnt(2) lgkmcnt(0)" ::: "memory");
  __builtin_amdgcn_sched_barrier(0);
  __builtin_amdgcn_s_barrier();
}
__device__ __forceinline__ void pipe_barrier_v0() {
  asm volatile("s_waitcnt vmcnt(0) lgkmcnt(0)" ::: "memory");
  __builtin_amdgcn_sched_barrier(0);
  __builtin_amdgcn_s_barrier();
}

// ---------- prep: cast x -> f16 ; transpose Wqkv, Wproj -> f16 ----------
// blocks [0,4096): cast; [4096,7168): Wqkv^T; [7168,8192): Wproj^T
__global__ __launch_bounds__(256) void prep_kernel(
    const float* __restrict__ x, _Float16* __restrict__ xf,
    const float* __restrict__ Wqkv, _Float16* __restrict__ wqt,
    const float* __restrict__ Wproj, _Float16* __restrict__ wpt) {
  __shared__ float tile[32][33];
  const int bx = blockIdx.x;
  if (bx < 4096) {
    const int i = bx * 256 + threadIdx.x;
    f32x4 v = *(const f32x4*)(x + (size_t)i * 4);
    f16x4 h;
#pragma unroll
    for (int j = 0; j < 4; ++j) h[j] = (_Float16)v[j];
    *(f16x4*)(xf + (size_t)i * 4) = h;
    return;
  }
  const float* W;
  _Float16* wt;
  int N, n0, k0;
  if (bx < 7168) {
    const int t = bx - 4096;
    W = Wqkv; wt = wqt; N = 3072;
    n0 = (t % 96) * 32; k0 = (t / 96) * 32;
  } else {
    const int t = bx - 7168;
    W = Wproj; wt = wpt; N = 1024;
    n0 = (t % 32) * 32; k0 = (t / 32) * 32;
  }
  const int tx = threadIdx.x & 31, ty = threadIdx.x >> 5;  // 32x8
#pragma unroll
  for (int j = 0; j < 32; j += 8)
    tile[ty + j][tx] = W[(size_t)(k0 + ty + j) * N + n0 + tx];
  __syncthreads();
#pragma unroll
  for (int j = 0; j < 32; j += 8)
    wt[(size_t)(n0 + ty + j) * 1024 + k0 + tx] = (_Float16)tile[tx][ty + j];
}

// ---------- GEMM: qkv = x @ Wqkv + b, 3-buf counted-vmcnt pipe, XCD swizzle ----
__global__ __launch_bounds__(256) void gemm_qkv_kernel(
    const _Float16* __restrict__ xf, const _Float16* __restrict__ wt,
    const float* __restrict__ bias, _Float16* __restrict__ QF,
    _Float16* __restrict__ KF, _Float16* __restrict__ KT,
    _Float16* __restrict__ VT) {
  __shared__ __attribute__((aligned(16))) _Float16 lg[24576];
  const int tid = threadIdx.x, lane = tid & 63, w = tid >> 6;
  const int wg = blockIdx.x;
  const int cx = wg & 7, c = wg >> 3;  // c in [0,96)
  const int bxl = (cx & 1) * 12 + c % 12;   // 0..23
  const int byl = (cx >> 1) * 8 + c / 12;   // 0..31
  const int m0 = byl * 128, n0 = bxl * 128;
  const int wr = (w >> 1) * 64, wc = (w & 1) * 64;
  f32x4 acc[4][4] = {};

  const int srow = lane >> 2;
  const int scol = (((lane & 3) ^ ((lane >> 3) & 3)) * 8);
  const int fr = lane & 15, fg = lane >> 4;
  const int rswz = (fr >> 1) & 3;

  auto stageT = [&](int buf, int k0) {
#pragma unroll
    for (int j = 0; j < 2; ++j) {
      const int rbase = 32 * w + 16 * j;
      const int r = rbase + srow;
      gload_lds16(xf + (size_t)(m0 + r) * 1024 + k0 + scol,
                  &lg[buf * 8192 + rbase * 32]);
      gload_lds16(wt + (size_t)(n0 + r) * 1024 + k0 + scol,
                  &lg[buf * 8192 + 4096 + rbase * 32]);
    }
  };
  auto mfma_step = [&](int ab) {
    f16x8 af[4], bfr[4];
#pragma unroll
    for (int m = 0; m < 4; ++m)
      af[m] = *(const f16x8*)&lg[ab + (wr + 16 * m + fr) * 32 + ((fg ^ rswz) * 8)];
#pragma unroll
    for (int n = 0; n < 4; ++n)
      bfr[n] = *(const f16x8*)&lg[ab + 4096 + (wc + 16 * n + fr) * 32 + ((fg ^ rswz) * 8)];
#pragma unroll
    for (int m = 0; m < 4; ++m)
#pragma unroll
      for (int n = 0; n < 4; ++n) acc[m][n] = MFMA_F16(af[m], bfr[n], acc[m][n]);
  };

  stageT(0, 0);
  stageT(1, 32);
  pipe_barrier_v4();
  for (int T = 0; T < 30; T += 3) {
#pragma unroll
    for (int s = 0; s < 3; ++s) {   // s == t%3 == cur (compile-time)
      stageT((s + 2) % 3, (T + s + 2) * 32);
      mfma_step(s * 8192);
      pipe_barrier_v4();
    }
  }
  mfma_step(0);        // t=30
  pipe_barrier_v0();
  mfma_step(8192);     // t=31
  pipe_barrier_v0();

  const int fq = fg * 4;
#pragma unroll
  for (int n = 0; n < 4; ++n) {
    const float bv = bias[n0 + wc + 16 * n + fr];
#pragma unroll
    for (int m = 0; m < 4; ++m)
#pragma unroll
      for (int i = 0; i < 4; ++i)
        lg[(wr + 16 * m + fq + i) * 129 + wc + 16 * n + fr] =
            (_Float16)(acc[m][n][i] + bv);
  }
  __syncthreads();
  const int b = m0 >> 11, nnb = m0 & 2047;
  const int h0 = 2 * (bxl & 7);
  const int sPhase = bxl >> 3;  // 0=Q 1=K 2=V (uniform per block)
  if (sPhase <= 1) {
    _Float16* __restrict__ dst = (sPhase == 0) ? QF : KF;
#pragma unroll
    for (int p = 0; p < 8; ++p) {
      const int r = p * 16 + (tid >> 4);
      const int cc = tid & 15;
      f16x8 vals;
#pragma unroll
      for (int j = 0; j < 8; ++j) vals[j] = lg[r * 129 + cc * 8 + j];
      const int h = cc >> 3, d = (cc & 7) * 8;
      *(f16x8*)&dst[((size_t)((b * 16 + h0 + h) * 2048 + nnb + r)) * 64 + d] = vals;
    }
  }
  if (sPhase >= 1) {
    _Float16* __restrict__ T = (sPhase == 1) ? KT : VT;
#pragma unroll
    for (int p = 0; p < 8; ++p) {
      const int lr = p * 16 + (tid >> 4);
      const int cc = tid & 15;
      f16x8 vals;
#pragma unroll
      for (int j = 0; j < 8; ++j) vals[j] = lg[(cc * 8 + j) * 129 + lr];
      const int h = lr >> 6, d = lr & 63;
      *(f16x8*)&T[((size_t)((b * 16 + h0 + h) * 64 + d)) * 2048 + nnb + cc * 8] = vals;
    }
  }
}

// ---------- Gram partial: 256 WGs, each 256 keys of one head (f32 out) ------
__global__ __launch_bounds__(256) void gram_partial_kernel(
    const _Float16* __restrict__ KT, float* __restrict__ GP) {
  __shared__ __attribute__((aligned(16))) _Float16 sT[3][4096];
  const int tid = threadIdx.x, lane = tid & 63, w = tid >> 6;
  const int bh = blockIdx.x >> 3, qt = blockIdx.x & 7;
  const _Float16* src = KT + (size_t)bh * 64 * 2048 + qt * 256;
  const int s_r = lane >> 3, s_cg = lane & 7;
  const int fr = lane & 15, fg = lane >> 4;
  const int kswz = fr & 7;

  auto stage = [&](int buf, int n0) {
#pragma unroll
    for (int j = 0; j < 2; ++j) {
      const int rbase = 8 * w + 32 * j;
      gload_lds16(src + (size_t)(rbase + s_r) * 2048 + n0 + ((s_cg ^ s_r) * 8),
                  &sT[buf][rbase * 64]);
    }
  };
  f32x4 acc[4] = {};
  auto mm = [&](int buf) {
    f16x8 af[2];
#pragma unroll
    for (int ks = 0; ks < 2; ++ks)
      af[ks] = *(const f16x8*)&sT[buf][(16 * w + fr) * 64 + (((ks * 4 + fg) ^ kswz) * 8)];
#pragma unroll
    for (int nt = 0; nt < 4; ++nt)
#pragma unroll
      for (int ks = 0; ks < 2; ++ks)
        acc[nt] = MFMA_F16(
            af[ks],
            *(const f16x8*)&sT[buf][(16 * nt + fr) * 64 + (((ks * 4 + fg) ^ kswz) * 8)],
            acc[nt]);
  };

  stage(0, 0);
  stage(1, 64);
  pipe_barrier_v2();
  stage(2, 128); mm(0); pipe_barrier_v2();
  stage(0, 192); mm(1); pipe_barrier_v2();
  mm(2); pipe_barrier_v0();
  mm(0);

  float* dst = GP + (size_t)blockIdx.x * 4096;
#pragma unroll
  for (int nt = 0; nt < 4; ++nt)
#pragma unroll
    for (int i = 0; i < 4; ++i)
      dst[(16 * w + fg * 4 + i) * 64 + 16 * nt + fr] = acc[nt][i];
}

// ---------- Gram reduce: sum 8 partials -> split f16 hi/lo ----------
__global__ __launch_bounds__(256) void gram_reduce_kernel(
    const float* __restrict__ GP, _Float16* __restrict__ GH,
    _Float16* __restrict__ GL) {
  const int bh = blockIdx.x >> 2, seg = blockIdx.x & 3;
  const int e0 = seg * 1024 + threadIdx.x * 4;
  const float* p = GP + (size_t)bh * 8 * 4096 + e0;
  f32x4 s = *(const f32x4*)p;
#pragma unroll
  for (int o = 1; o < 8; ++o) s += *(const f32x4*)(p + o * 4096);
  f16x4 gh, gl;
#pragma unroll
  for (int j = 0; j < 4; ++j) {
    gh[j] = (_Float16)s[j];
    gl[j] = (_Float16)(s[j] - (float)gh[j]);
  }
  *(f16x4*)&GH[(size_t)bh * 4096 + e0] = gh;
  *(f16x4*)&GL[(size_t)bh * 4096 + e0] = gl;
}

// ---------- attention: 128 q-rows/WG; swapped QK^T, P in registers,
// 4-buf stage-3-ahead counted-vmcnt pipeline + cross-tile overlap.
// minvl2 pre-folded into Q fragments; lsum via ones-MFMA. (identical to r14)
// LDS (f16 idx): K bufs @ b*4096 (b=0..3) | VT bufs @ 16384 + b*4096. 64KB.
__global__ __launch_bounds__(256) void attn_kernel(
    const _Float16* __restrict__ QF, const _Float16* __restrict__ KF,
    const _Float16* __restrict__ VT, const _Float16* __restrict__ GH,
    const _Float16* __restrict__ GL, _Float16* __restrict__ OB,
    const float* __restrict__ sigma_p, const float* __restrict__ gamma_p) {
  __shared__ __attribute__((aligned(16))) _Float16 lds[32768];

  const int tid = threadIdx.x, lane = tid & 63, w = tid >> 6;
  const int wg = blockIdx.x;
  const int c = wg >> 3;                  // 0..63
  const int bh = (wg & 7) * 4 + (c >> 4); // b*16 + h
  const int q0 = (c & 15) * 128;
  const size_t base = (size_t)bh * (2048 * 64);
  const float sigma = sigma_p[0], gamma = gamma_p[0];
  const int fr = lane & 15, fg = lane >> 4;
  const int s_r = lane >> 3, s_cg = lane & 7;
  const int kswz = fr & 7;

  const _Float16* Kbh = KF + base;
  const _Float16* Tbh = VT + base;  // [64 d][2048 n]

  f16x8 qf[2][2];
#pragma unroll
  for (int m = 0; m < 2; ++m)
#pragma unroll
    for (int ks = 0; ks < 2; ++ks)
      qf[m][ks] = *(const f16x8*)(QF + base +
                                  (size_t)(q0 + 32 * w + 16 * m + fr) * 64 +
                                  ks * 32 + fg * 8);

  auto stage64 = [&](int dstoff, const _Float16* g, int srcstride) {
#pragma unroll
    for (int j = 0; j < 2; ++j) {
      const int rbase = 8 * w + 32 * j;
      gload_lds16(g + (size_t)(rbase + s_r) * srcstride + ((s_cg ^ s_r) * 8),
                  &lds[dstoff + rbase * 64]);
    }
  };
  auto stage64K = [&](int dstoff, const _Float16* g) {
#pragma unroll
    for (int j = 0; j < 2; ++j) {
      const int rbase = 8 * w + 32 * j;
      const int r = rbase + s_r;
      const int pr = (r & 0x23) | ((r & 0x0C) << 1) | ((r & 0x10) >> 2);
      gload_lds16(g + (size_t)pr * 64 + ((s_cg ^ s_r) * 8),
                  &lds[dstoff + rbase * 64]);
    }
  };
  auto stage_tile = [&](int b, int kb) {
    stage64K(b * 4096, Kbh + (size_t)kb * 4096);
    stage64(16384 + b * 4096, Tbh + kb * 64, 2048);
  };

  // ---- prologue: minvl2 from q^T G q ----
  stage64(0, GH + (size_t)bh * 4096, 64);
  stage64(4096, GL + (size_t)bh * 4096, 64);
  __syncthreads();
  float minvl2[2];
  float* Yp = (float*)&lds[8192 + w * 2048];
#pragma unroll
  for (int m = 0; m < 2; ++m) {
    f32x4 yacc[4] = {};
#pragma unroll
    for (int nt = 0; nt < 4; ++nt) {
#pragma unroll
      for (int ks = 0; ks < 2; ++ks) {
        const int off = (16 * nt + fr) * 64 + (((ks * 4 + fg) ^ kswz) * 8);
        yacc[nt] = MFMA_F16(qf[m][ks], *(const f16x8*)&lds[off], yacc[nt]);
        yacc[nt] = MFMA_F16(qf[m][ks], *(const f16x8*)&lds[4096 + off], yacc[nt]);
      }
    }
#pragma unroll
    for (int nt = 0; nt < 4; ++nt)
#pragma unroll
      for (int i = 0; i < 4; ++i) Yp[(fg * 4 + i) * 64 + 16 * nt + fr] = yacc[nt][i];
    float zp = 0.0f;
#pragma unroll
    for (int ks = 0; ks < 2; ++ks) {
      const f32x4 y0 = *(const f32x4*)&Yp[fr * 64 + ks * 32 + fg * 8];
      const f32x4 y1 = *(const f32x4*)&Yp[fr * 64 + ks * 32 + fg * 8 + 4];
#pragma unroll
      for (int cc = 0; cc < 4; ++cc) {
        zp += y0[cc] * (float)qf[m][ks][cc];
        zp += y1[cc] * (float)qf[m][ks][cc + 4];
      }
    }
    zp += __shfl_xor(zp, 16);
    zp += __shfl_xor(zp, 32);
    const float rms = sqrtf(fmaxf(zp, 0.0f)) * (1.0f / 362.038672f);
    minvl2[m] = gamma / (sigma + rms) * 0.125f * 1.44269504f;  // fold log2(e)
  }
#pragma unroll
  for (int m = 0; m < 2; ++m)
#pragma unroll
    for (int ks = 0; ks < 2; ++ks) {
      f16x8 q = qf[m][ks], r;
#pragma unroll
      for (int j = 0; j < 4; ++j) {
        const f16x2 t = pk2((float)q[2 * j] * minvl2[m],
                            (float)q[2 * j + 1] * minvl2[m]);
        r[2 * j] = t[0];
        r[2 * j + 1] = t[1];
      }
      qf[m][ks] = r;
    }
  __syncthreads();

  f32x4 oacc[2][4] = {};
  f32x4 lacc[2] = {};
  f16x8 ones;
#pragma unroll
  for (int j = 0; j < 8; ++j) ones[j] = (_Float16)1.0f;

  auto qk_tile = [&](int kbuf, f32x4 (&pn)[2][4]) {
#pragma unroll
    for (int n = 0; n < 4; ++n) {
      const int offb = kbuf * 4096 + (16 * n + fr) * 64;
      const f16x8 kf0 = *(const f16x8*)&lds[offb + ((fg ^ kswz) * 8)];
      const f16x8 kf1 = *(const f16x8*)&lds[offb + (((4 + fg) ^ kswz) * 8)];
#pragma unroll
      for (int m = 0; m < 2; ++m) {
        f32x4 a = {};
        a = MFMA_F16(kf0, qf[m][0], a);
        a = MFMA_F16(kf1, qf[m][1], a);
        pn[m][n] = a;
      }
    }
  };
  auto exp_pack = [&](f32x4 (&pn)[2][4], f16x8 (&pa)[2][2]) {
#pragma unroll
    for (int m = 0; m < 2; ++m) {
#pragma unroll
      for (int n = 0; n < 4; ++n)
#pragma unroll
        for (int i = 0; i < 4; ++i)
          pn[m][n][i] = __builtin_amdgcn_exp2f(pn[m][n][i]);
#pragma unroll
      for (int k2 = 0; k2 < 2; ++k2) {
        const f16x2 c0 = pk2(pn[m][2 * k2][0], pn[m][2 * k2][1]);
        const f16x2 c1 = pk2(pn[m][2 * k2][2], pn[m][2 * k2][3]);
        const f16x2 c2 = pk2(pn[m][2 * k2 + 1][0], pn[m][2 * k2 + 1][1]);
        const f16x2 c3 = pk2(pn[m][2 * k2 + 1][2], pn[m][2 * k2 + 1][3]);
        pa[m][k2][0] = c0[0]; pa[m][k2][1] = c0[1];
        pa[m][k2][2] = c1[0]; pa[m][k2][3] = c1[1];
        pa[m][k2][4] = c2[0]; pa[m][k2][5] = c2[1];
        pa[m][k2][6] = c3[0]; pa[m][k2][7] = c3[1];
      }
    }
  };
  auto pv_tile = [&](int vbuf, f16x8 (&pa)[2][2]) {
#pragma unroll
    for (int k2 = 0; k2 < 2; ++k2) {
#pragma unroll
      for (int nf = 0; nf < 4; ++nf) {
        const int off = 16384 + vbuf * 4096 + (16 * nf + fr) * 64 +
                        (((k2 * 4 + fg) ^ kswz) * 8);
        const f16x8 vt = *(const f16x8*)&lds[off];
        oacc[0][nf] = MFMA_F16(vt, pa[0][k2], oacc[0][nf]);
        oacc[1][nf] = MFMA_F16(vt, pa[1][k2], oacc[1][nf]);
      }
      lacc[0] = MFMA_F16(ones, pa[0][k2], lacc[0]);
      lacc[1] = MFMA_F16(ones, pa[1][k2], lacc[1]);
    }
  };

  f32x4 pn[2][4];
  f16x8 pa[2][2][2];  // [ping][m][k2]

  stage_tile(0, 0);
  stage_tile(1, 1);
  stage_tile(2, 2);
  pipe_barrier_v4();
  qk_tile(0, pn);
  exp_pack(pn, pa[0]);

  for (int T = 0; T < 28; T += 4) {
#pragma unroll
    for (int s = 0; s < 4; ++s) {   // t = T+s ; t&3 == s
      stage_tile((s + 3) & 3, T + s + 3);
      __builtin_amdgcn_s_setprio(1);
      qk_tile((s + 1) & 3, pn);
      __builtin_amdgcn_s_setprio(0);
      __builtin_amdgcn_s_setprio(1);
      pv_tile(s & 3, pa[s & 1]);
      __builtin_amdgcn_s_setprio(0);
      exp_pack(pn, pa[(s + 1) & 1]);
      pipe_barrier_v4();
    }
  }
  {
    stage_tile(3, 31);
    __builtin_amdgcn_s_setprio(1); qk_tile(1, pn); __builtin_amdgcn_s_setprio(0);
    __builtin_amdgcn_s_setprio(1); pv_tile(0, pa[0]); __builtin_amdgcn_s_setprio(0);
    exp_pack(pn, pa[1]);
    pipe_barrier_v4();
    __builtin_amdgcn_s_setprio(1); qk_tile(2, pn); __builtin_amdgcn_s_setprio(0);
    __builtin_amdgcn_s_setprio(1); pv_tile(1, pa[1]); __builtin_amdgcn_s_setprio(0);
    exp_pack(pn, pa[0]);
    pipe_barrier_v0();
    __builtin_amdgcn_s_setprio(1); qk_tile(3, pn); __builtin_amdgcn_s_setprio(0);
    __builtin_amdgcn_s_setprio(1); pv_tile(2, pa[0]); __builtin_amdgcn_s_setprio(0);
    exp_pack(pn, pa[1]);
    pipe_barrier_v0();
    __builtin_amdgcn_s_setprio(1); pv_tile(3, pa[1]); __builtin_amdgcn_s_setprio(0);
  }

  float inv[2];
#pragma unroll
  for (int m = 0; m < 2; ++m) inv[m] = 1.0f / lacc[m][0];

  const int b = bh >> 4, h = bh & 15;
#pragma unroll
  for (int m = 0; m < 2; ++m) {
    const size_t orow = (size_t)(b * 2048 + q0 + 32 * w + 16 * m + fr);
#pragma unroll
    for (int nf = 0; nf < 4; ++nf) {
      f16x4 ov;
#pragma unroll
      for (int i = 0; i < 4; ++i) ov[i] = (_Float16)(oacc[m][nf][i] * inv[m]);
      *(f16x4*)&OB[orow * 1024 + h * 64 + 16 * nf + 4 * fg] = ov;
    }
  }
}

// ---------- GEMM: out = O @ Wproj + b, f32 out, BM=64 tiles, 3-buf pipe ------
__global__ __launch_bounds__(256) void gemm_proj_kernel(
    const _Float16* __restrict__ A, const _Float16* __restrict__ Bt,
    const float* __restrict__ bias, float* __restrict__ out) {
  __shared__ __attribute__((aligned(16))) _Float16 lg[18432];
  const int tid = threadIdx.x, lane = tid & 63, w = tid >> 6;
  const int wg = blockIdx.x;
  const int c = wg >> 3;                       // 0..63
  const int bxl = c & 7;                       // 0..7
  const int byl = (wg & 7) * 8 + (c >> 3);     // 0..63
  const int m0 = byl * 64, n0 = bxl * 128;
  const int wr = (w >> 1) * 32, wc = (w & 1) * 64;
  f32x4 acc[2][4] = {};
  const int srow = lane >> 2;
  const int scol = (((lane & 3) ^ ((lane >> 3) & 3)) * 8);
  const int fr = lane & 15, fg = lane >> 4;
  const int rswz = (fr >> 1) & 3;

  auto stageT = [&](int buf, int k0) {
    {
      const int rbase = 16 * w;
      gload_lds16(A + (size_t)(m0 + rbase + srow) * 1024 + k0 + scol,
                  &lg[buf * 6144 + rbase * 32]);
    }
#pragma unroll
    for (int j = 0; j < 2; ++j) {
      const int rbase = 32 * w + 16 * j;
      gload_lds16(Bt + (size_t)(n0 + rbase + srow) * 1024 + k0 + scol,
                  &lg[buf * 6144 + 2048 + rbase * 32]);
    }
  };
  auto mfma_step = [&](int ab) {
    f16x8 af[2], bfr[4];
#pragma unroll
    for (int m = 0; m < 2; ++m)
      af[m] = *(const f16x8*)&lg[ab + (wr + 16 * m + fr) * 32 + ((fg ^ rswz) * 8)];
#pragma unroll
    for (int n = 0; n < 4; ++n)
      bfr[n] = *(const f16x8*)&lg[ab + 2048 + (wc + 16 * n + fr) * 32 + ((fg ^ rswz) * 8)];
#pragma unroll
    for (int m = 0; m < 2; ++m)
#pragma unroll
      for (int n = 0; n < 4; ++n) acc[m][n] = MFMA_F16(af[m], bfr[n], acc[m][n]);
  };

  stageT(0, 0);
  stageT(1, 32);
  pipe_barrier_v3();
  for (int T = 0; T < 30; T += 3) {
#pragma unroll
    for (int s = 0; s < 3; ++s) {
      stageT((s + 2) % 3, (T + s + 2) * 32);
      mfma_step(s * 6144);
      pipe_barrier_v3();
    }
  }
  mfma_step(0);       // t=30
  pipe_barrier_v0();
  mfma_step(6144);    // t=31
  pipe_barrier_v0();

  const int fq = fg * 4;
#pragma unroll
  for (int n = 0; n < 4; ++n) {
    const int col = n0 + wc + 16 * n + fr;
    const float bv = bias[col];
#pragma unroll
    for (int m = 0; m < 2; ++m) {
#pragma unroll
      for (int i = 0; i < 4; ++i) {
        const int row = m0 + wr + 16 * m + fq + i;
        out[(size_t)row * 1024 + col] = acc[m][n][i] + bv;
      }
    }
  }
}

// ---------- launch ----------
extern "C" void kernel_launch(void* const* d_in, const int* in_sizes, int n_in,
                              void* d_out, int out_size, void* d_ws, size_t ws_size,
                              hipStream_t stream) {
  const float* x = (const float*)d_in[0];
  const float* Wqkv = (const float*)d_in[1];
  const float* bqkv = (const float*)d_in[2];
  const float* Wproj = (const float*)d_in[3];
  const float* bproj = (const float*)d_in[4];
  const float* sigma = (const float*)d_in[5];
  const float* gamma = (const float*)d_in[6];
  float* out = (float*)d_out;

  char* ws = (char*)d_ws;
  const size_t MB = 1024 * 1024;
  _Float16* XF  = (_Float16*)(ws + 0 * MB);   // 8MB  x (f16)
  _Float16* WQT = (_Float16*)(ws + 8 * MB);   // 6MB  Wqkv^T (dead after qkv GEMM)
  _Float16* WPT = (_Float16*)(ws + 14 * MB);  // 2MB  Wproj^T
  _Float16* QF  = (_Float16*)(ws + 16 * MB);  // 8MB  [B,H,N,D]
  _Float16* KF  = (_Float16*)(ws + 24 * MB);  // 8MB  [B,H,N,D]
  _Float16* VT  = (_Float16*)(ws + 32 * MB);  // 8MB  [B,H,D,N]
  _Float16* KT  = (_Float16*)(ws + 40 * MB);  // 8MB  (dead after gram)
  _Float16* OB  = (_Float16*)(ws + 40 * MB);  // 8MB  attn out (over KT)
  _Float16* GH  = (_Float16*)(ws + 8 * MB);   // 256KB Gram hi (over dead WQT)
  _Float16* GL  = (_Float16*)(ws + 8 * MB + 512 * 1024);  // 256KB Gram lo
  float*    GP  = (float*)(ws + 9 * MB);      // 4MB  Gram partials (f32, 256x4096)

  prep_kernel<<<8192, 256, 0, stream>>>(x, XF, Wqkv, WQT, Wproj, WPT);
  gemm_qkv_kernel<<<768, 256, 0, stream>>>(XF, WQT, bqkv, QF, KF, KT, VT);
  gram_partial_kernel<<<256, 256, 0, stream>>>(KT, GP);
  gram_reduce_kernel<<<128, 256, 0, stream>>>(GP, GH, GL);
  attn_kernel<<<512, 256, 0, stream>>>(QF, KF, VT, GH, GL, OB, sigma, gamma);
  gemm_proj_kernel<<<512, 256, 0, stream>>>(OB, WPT, bproj, out);
}

// Round 17
// 114.302 us; speedup vs baseline: 1.2316x; 1.0188x over previous
//
#include <hip/hip_runtime.h>

// ---------- types / helpers ----------
typedef __attribute__((ext_vector_type(4))) float f32x4;
typedef __attribute__((ext_vector_type(8))) _Float16 f16x8;
typedef __attribute__((ext_vector_type(4))) _Float16 f16x4;
typedef __attribute__((ext_vector_type(2))) _Float16 f16x2;

#define MFMA_F16(a, b, c) __builtin_amdgcn_mfma_f32_16x16x32_f16(a, b, c, 0, 0, 0)

__device__ __forceinline__ void gload_lds16(const void* g, void* l) {
  // async global->LDS, 16B/lane; LDS dest is wave-uniform base + lane*16
  __builtin_amdgcn_global_load_lds(
      (const __attribute__((address_space(1))) void*)g,
      (__attribute__((address_space(3))) void*)l, 16, 0, 0);
}
__device__ __forceinline__ f16x2 pk2(float a, float b) {
  return __builtin_bit_cast(f16x2, __builtin_amdgcn_cvt_pkrtz(a, b));
}
// counted-vmcnt pipeline barriers
__device__ __forceinline__ void pipe_barrier_v4() {
  asm volatile("s_waitcnt vmcnt(4) lgkmcnt(0)" ::: "memory");
  __builtin_amdgcn_sched_barrier(0);
  __builtin_amdgcn_s_barrier();
}
__device__ __forceinline__ void pipe_barrier_v3() {
  asm volatile("s_waitcnt vmcnt(3) lgkmcnt(0)" ::: "memory");
  __builtin_amdgcn_sched_barrier(0);
  __builtin_amdgcn_s_barrier();
}
__device__ __forceinline__ void pipe_barrier_v2() {
  asm volatile("s_waitcnt vmcnt(2) lgkmcnt(0)" ::: "memory");
  __builtin_amdgcn_sched_barrier(0);
  __builtin_amdgcn_s_barrier();
}
__device__ __forceinline__ void pipe_barrier_v0() {
  asm volatile("s_waitcnt vmcnt(0) lgkmcnt(0)" ::: "memory");
  __builtin_amdgcn_sched_barrier(0);
  __builtin_amdgcn_s_barrier();
}

// ---------- prep: cast x -> f16 ; transpose Wqkv, Wproj -> f16 ----------
// blocks [0,4096): cast; [4096,7168): Wqkv^T; [7168,8192): Wproj^T
__global__ __launch_bounds__(256) void prep_kernel(
    const float* __restrict__ x, _Float16* __restrict__ xf,
    const float* __restrict__ Wqkv, _Float16* __restrict__ wqt,
    const float* __restrict__ Wproj, _Float16* __restrict__ wpt) {
  __shared__ float tile[32][33];
  const int bx = blockIdx.x;
  if (bx < 4096) {
    const int i = bx * 256 + threadIdx.x;
    f32x4 v = *(const f32x4*)(x + (size_t)i * 4);
    f16x4 h;
#pragma unroll
    for (int j = 0; j < 4; ++j) h[j] = (_Float16)v[j];
    *(f16x4*)(xf + (size_t)i * 4) = h;
    return;
  }
  const float* W;
  _Float16* wt;
  int N, n0, k0;
  if (bx < 7168) {
    const int t = bx - 4096;
    W = Wqkv; wt = wqt; N = 3072;
    n0 = (t % 96) * 32; k0 = (t / 96) * 32;
  } else {
    const int t = bx - 7168;
    W = Wproj; wt = wpt; N = 1024;
    n0 = (t % 32) * 32; k0 = (t / 32) * 32;
  }
  const int tx = threadIdx.x & 31, ty = threadIdx.x >> 5;  // 32x8
#pragma unroll
  for (int j = 0; j < 32; j += 8)
    tile[ty + j][tx] = W[(size_t)(k0 + ty + j) * N + n0 + tx];
  __syncthreads();
#pragma unroll
  for (int j = 0; j < 32; j += 8)
    wt[(size_t)(n0 + ty + j) * 1024 + k0 + tx] = (_Float16)tile[tx][ty + j];
}

// ---------- GEMM: qkv = x @ Wqkv + b, 3-buf counted-vmcnt pipe ----------
// XCD chunking: 16 chunks of 6 cols x 8 rows (48 WGs); per-chunk resident
// set = A 2MB + B 1.5MB = 3.5MB < 4MB L2 (was 12x8 = 5MB -> thrash).
__global__ __launch_bounds__(256) void gemm_qkv_kernel(
    const _Float16* __restrict__ xf, const _Float16* __restrict__ wt,
    const float* __restrict__ bias, _Float16* __restrict__ QF,
    _Float16* __restrict__ KF, _Float16* __restrict__ KT,
    _Float16* __restrict__ VT) {
  __shared__ __attribute__((aligned(16))) _Float16 lg[24576];
  const int tid = threadIdx.x, lane = tid & 63, w = tid >> 6;
  const int wg = blockIdx.x;
  const int xcd = wg & 7;
  const int c = wg >> 3;          // 0..95
  const int half = c / 48;        // 0..1 (second chunk wave per XCD)
  const int cc = c % 48;          // 0..47
  const int bxl = half * 12 + (xcd & 1) * 6 + cc % 6;   // 0..23
  const int byl = (xcd >> 1) * 8 + cc / 6;              // 0..31
  const int m0 = byl * 128, n0 = bxl * 128;
  const int wr = (w >> 1) * 64, wc = (w & 1) * 64;
  f32x4 acc[4][4] = {};

  const int srow = lane >> 2;
  const int scol = (((lane & 3) ^ ((lane >> 3) & 3)) * 8);
  const int fr = lane & 15, fg = lane >> 4;
  const int rswz = (fr >> 1) & 3;

  auto stageT = [&](int buf, int k0) {
#pragma unroll
    for (int j = 0; j < 2; ++j) {
      const int rbase = 32 * w + 16 * j;
      const int r = rbase + srow;
      gload_lds16(xf + (size_t)(m0 + r) * 1024 + k0 + scol,
                  &lg[buf * 8192 + rbase * 32]);
      gload_lds16(wt + (size_t)(n0 + r) * 1024 + k0 + scol,
                  &lg[buf * 8192 + 4096 + rbase * 32]);
    }
  };
  auto mfma_step = [&](int ab) {
    f16x8 af[4], bfr[4];
#pragma unroll
    for (int m = 0; m < 4; ++m)
      af[m] = *(const f16x8*)&lg[ab + (wr + 16 * m + fr) * 32 + ((fg ^ rswz) * 8)];
#pragma unroll
    for (int n = 0; n < 4; ++n)
      bfr[n] = *(const f16x8*)&lg[ab + 4096 + (wc + 16 * n + fr) * 32 + ((fg ^ rswz) * 8)];
#pragma unroll
    for (int m = 0; m < 4; ++m)
#pragma unroll
      for (int n = 0; n < 4; ++n) acc[m][n] = MFMA_F16(af[m], bfr[n], acc[m][n]);
  };

  stageT(0, 0);
  stageT(1, 32);
  pipe_barrier_v4();
  for (int T = 0; T < 30; T += 3) {
#pragma unroll
    for (int s = 0; s < 3; ++s) {   // s == t%3 == cur (compile-time)
      stageT((s + 2) % 3, (T + s + 2) * 32);
      mfma_step(s * 8192);
      pipe_barrier_v4();
    }
  }
  mfma_step(0);        // t=30
  pipe_barrier_v0();
  mfma_step(8192);     // t=31
  pipe_barrier_v0();

  const int fq = fg * 4;
#pragma unroll
  for (int n = 0; n < 4; ++n) {
    const float bv = bias[n0 + wc + 16 * n + fr];
#pragma unroll
    for (int m = 0; m < 4; ++m)
#pragma unroll
      for (int i = 0; i < 4; ++i)
        lg[(wr + 16 * m + fq + i) * 129 + wc + 16 * n + fr] =
            (_Float16)(acc[m][n][i] + bv);
  }
  __syncthreads();
  const int b = m0 >> 11, nnb = m0 & 2047;
  const int h0 = 2 * (bxl & 7);
  const int sPhase = bxl >> 3;  // 0=Q 1=K 2=V (uniform per block)
  if (sPhase <= 1) {
    _Float16* __restrict__ dst = (sPhase == 0) ? QF : KF;
#pragma unroll
    for (int p = 0; p < 8; ++p) {
      const int r = p * 16 + (tid >> 4);
      const int cci = tid & 15;
      f16x8 vals;
#pragma unroll
      for (int j = 0; j < 8; ++j) vals[j] = lg[r * 129 + cci * 8 + j];
      const int h = cci >> 3, d = (cci & 7) * 8;
      *(f16x8*)&dst[((size_t)((b * 16 + h0 + h) * 2048 + nnb + r)) * 64 + d] = vals;
    }
  }
  if (sPhase >= 1) {
    _Float16* __restrict__ T = (sPhase == 1) ? KT : VT;
#pragma unroll
    for (int p = 0; p < 8; ++p) {
      const int lr = p * 16 + (tid >> 4);
      const int cci = tid & 15;
      f16x8 vals;
#pragma unroll
      for (int j = 0; j < 8; ++j) vals[j] = lg[(cci * 8 + j) * 129 + lr];
      const int h = lr >> 6, d = lr & 63;
      *(f16x8*)&T[((size_t)((b * 16 + h0 + h) * 64 + d)) * 2048 + nnb + cci * 8] = vals;
    }
  }
}

// ---------- Gram partial: 256 WGs, each 256 keys of one head (f32 out) ------
__global__ __launch_bounds__(256) void gram_partial_kernel(
    const _Float16* __restrict__ KT, float* __restrict__ GP) {
  __shared__ __attribute__((aligned(16))) _Float16 sT[3][4096];
  const int tid = threadIdx.x, lane = tid & 63, w = tid >> 6;
  const int bh = blockIdx.x >> 3, qt = blockIdx.x & 7;
  const _Float16* src = KT + (size_t)bh * 64 * 2048 + qt * 256;
  const int s_r = lane >> 3, s_cg = lane & 7;
  const int fr = lane & 15, fg = lane >> 4;
  const int kswz = fr & 7;

  auto stage = [&](int buf, int n0) {
#pragma unroll
    for (int j = 0; j < 2; ++j) {
      const int rbase = 8 * w + 32 * j;
      gload_lds16(src + (size_t)(rbase + s_r) * 2048 + n0 + ((s_cg ^ s_r) * 8),
                  &sT[buf][rbase * 64]);
    }
  };
  f32x4 acc[4] = {};
  auto mm = [&](int buf) {
    f16x8 af[2];
#pragma unroll
    for (int ks = 0; ks < 2; ++ks)
      af[ks] = *(const f16x8*)&sT[buf][(16 * w + fr) * 64 + (((ks * 4 + fg) ^ kswz) * 8)];
#pragma unroll
    for (int nt = 0; nt < 4; ++nt)
#pragma unroll
      for (int ks = 0; ks < 2; ++ks)
        acc[nt] = MFMA_F16(
            af[ks],
            *(const f16x8*)&sT[buf][(16 * nt + fr) * 64 + (((ks * 4 + fg) ^ kswz) * 8)],
            acc[nt]);
  };

  stage(0, 0);
  stage(1, 64);
  pipe_barrier_v2();
  stage(2, 128); mm(0); pipe_barrier_v2();
  stage(0, 192); mm(1); pipe_barrier_v2();
  mm(2); pipe_barrier_v0();
  mm(0);

  float* dst = GP + (size_t)blockIdx.x * 4096;
#pragma unroll
  for (int nt = 0; nt < 4; ++nt)
#pragma unroll
    for (int i = 0; i < 4; ++i)
      dst[(16 * w + fg * 4 + i) * 64 + 16 * nt + fr] = acc[nt][i];
}

// ---------- Gram reduce: sum 8 partials -> split f16 hi/lo ----------
__global__ __launch_bounds__(256) void gram_reduce_kernel(
    const float* __restrict__ GP, _Float16* __restrict__ GH,
    _Float16* __restrict__ GL) {
  const int bh = blockIdx.x >> 2, seg = blockIdx.x & 3;
  const int e0 = seg * 1024 + threadIdx.x * 4;
  const float* p = GP + (size_t)bh * 8 * 4096 + e0;
  f32x4 s = *(const f32x4*)p;
#pragma unroll
  for (int o = 1; o < 8; ++o) s += *(const f32x4*)(p + o * 4096);
  f16x4 gh, gl;
#pragma unroll
  for (int j = 0; j < 4; ++j) {
    gh[j] = (_Float16)s[j];
    gl[j] = (_Float16)(s[j] - (float)gh[j]);
  }
  *(f16x4*)&GH[(size_t)bh * 4096 + e0] = gh;
  *(f16x4*)&GL[(size_t)bh * 4096 + e0] = gl;
}

// ---------- attention: 128 q-rows/WG; swapped QK^T, P in registers,
// 4-buf stage-3-ahead counted-vmcnt pipeline + cross-tile overlap.
// minvl2 pre-folded into Q fragments; lsum via ones-MFMA. (identical to r14)
// LDS (f16 idx): K bufs @ b*4096 (b=0..3) | VT bufs @ 16384 + b*4096. 64KB.
__global__ __launch_bounds__(256) void attn_kernel(
    const _Float16* __restrict__ QF, const _Float16* __restrict__ KF,
    const _Float16* __restrict__ VT, const _Float16* __restrict__ GH,
    const _Float16* __restrict__ GL, _Float16* __restrict__ OB,
    const float* __restrict__ sigma_p, const float* __restrict__ gamma_p) {
  __shared__ __attribute__((aligned(16))) _Float16 lds[32768];

  const int tid = threadIdx.x, lane = tid & 63, w = tid >> 6;
  const int wg = blockIdx.x;
  const int c = wg >> 3;                  // 0..63
  const int bh = (wg & 7) * 4 + (c >> 4); // b*16 + h
  const int q0 = (c & 15) * 128;
  const size_t base = (size_t)bh * (2048 * 64);
  const float sigma = sigma_p[0], gamma = gamma_p[0];
  const int fr = lane & 15, fg = lane >> 4;
  const int s_r = lane >> 3, s_cg = lane & 7;
  const int kswz = fr & 7;

  const _Float16* Kbh = KF + base;
  const _Float16* Tbh = VT + base;  // [64 d][2048 n]

  f16x8 qf[2][2];
#pragma unroll
  for (int m = 0; m < 2; ++m)
#pragma unroll
    for (int ks = 0; ks < 2; ++ks)
      qf[m][ks] = *(const f16x8*)(QF + base +
                                  (size_t)(q0 + 32 * w + 16 * m + fr) * 64 +
                                  ks * 32 + fg * 8);

  auto stage64 = [&](int dstoff, const _Float16* g, int srcstride) {
#pragma unroll
    for (int j = 0; j < 2; ++j) {
      const int rbase = 8 * w + 32 * j;
      gload_lds16(g + (size_t)(rbase + s_r) * srcstride + ((s_cg ^ s_r) * 8),
                  &lds[dstoff + rbase * 64]);
    }
  };
  auto stage64K = [&](int dstoff, const _Float16* g) {
#pragma unroll
    for (int j = 0; j < 2; ++j) {
      const int rbase = 8 * w + 32 * j;
      const int r = rbase + s_r;
      const int pr = (r & 0x23) | ((r & 0x0C) << 1) | ((r & 0x10) >> 2);
      gload_lds16(g + (size_t)pr * 64 + ((s_cg ^ s_r) * 8),
                  &lds[dstoff + rbase * 64]);
    }
  };
  auto stage_tile = [&](int b, int kb) {
    stage64K(b * 4096, Kbh + (size_t)kb * 4096);
    stage64(16384 + b * 4096, Tbh + kb * 64, 2048);
  };

  // ---- prologue: minvl2 from q^T G q ----
  stage64(0, GH + (size_t)bh * 4096, 64);
  stage64(4096, GL + (size_t)bh * 4096, 64);
  __syncthreads();
  float minvl2[2];
  float* Yp = (float*)&lds[8192 + w * 2048];
#pragma unroll
  for (int m = 0; m < 2; ++m) {
    f32x4 yacc[4] = {};
#pragma unroll
    for (int nt = 0; nt < 4; ++nt) {
#pragma unroll
      for (int ks = 0; ks < 2; ++ks) {
        const int off = (16 * nt + fr) * 64 + (((ks * 4 + fg) ^ kswz) * 8);
        yacc[nt] = MFMA_F16(qf[m][ks], *(const f16x8*)&lds[off], yacc[nt]);
        yacc[nt] = MFMA_F16(qf[m][ks], *(const f16x8*)&lds[4096 + off], yacc[nt]);
      }
    }
#pragma unroll
    for (int nt = 0; nt < 4; ++nt)
#pragma unroll
      for (int i = 0; i < 4; ++i) Yp[(fg * 4 + i) * 64 + 16 * nt + fr] = yacc[nt][i];
    float zp = 0.0f;
#pragma unroll
    for (int ks = 0; ks < 2; ++ks) {
      const f32x4 y0 = *(const f32x4*)&Yp[fr * 64 + ks * 32 + fg * 8];
      const f32x4 y1 = *(const f32x4*)&Yp[fr * 64 + ks * 32 + fg * 8 + 4];
#pragma unroll
      for (int cc = 0; cc < 4; ++cc) {
        zp += y0[cc] * (float)qf[m][ks][cc];
        zp += y1[cc] * (float)qf[m][ks][cc + 4];
      }
    }
    zp += __shfl_xor(zp, 16);
    zp += __shfl_xor(zp, 32);
    const float rms = sqrtf(fmaxf(zp, 0.0f)) * (1.0f / 362.038672f);
    minvl2[m] = gamma / (sigma + rms) * 0.125f * 1.44269504f;  // fold log2(e)
  }
#pragma unroll
  for (int m = 0; m < 2; ++m)
#pragma unroll
    for (int ks = 0; ks < 2; ++ks) {
      f16x8 q = qf[m][ks], r;
#pragma unroll
      for (int j = 0; j < 4; ++j) {
        const f16x2 t = pk2((float)q[2 * j] * minvl2[m],
                            (float)q[2 * j + 1] * minvl2[m]);
        r[2 * j] = t[0];
        r[2 * j + 1] = t[1];
      }
      qf[m][ks] = r;
    }
  __syncthreads();

  f32x4 oacc[2][4] = {};
  f32x4 lacc[2] = {};
  f16x8 ones;
#pragma unroll
  for (int j = 0; j < 8; ++j) ones[j] = (_Float16)1.0f;

  auto qk_tile = [&](int kbuf, f32x4 (&pn)[2][4]) {
#pragma unroll
    for (int n = 0; n < 4; ++n) {
      const int offb = kbuf * 4096 + (16 * n + fr) * 64;
      const f16x8 kf0 = *(const f16x8*)&lds[offb + ((fg ^ kswz) * 8)];
      const f16x8 kf1 = *(const f16x8*)&lds[offb + (((4 + fg) ^ kswz) * 8)];
#pragma unroll
      for (int m = 0; m < 2; ++m) {
        f32x4 a = {};
        a = MFMA_F16(kf0, qf[m][0], a);
        a = MFMA_F16(kf1, qf[m][1], a);
        pn[m][n] = a;
      }
    }
  };
  auto exp_pack = [&](f32x4 (&pn)[2][4], f16x8 (&pa)[2][2]) {
#pragma unroll
    for (int m = 0; m < 2; ++m) {
#pragma unroll
      for (int n = 0; n < 4; ++n)
#pragma unroll
        for (int i = 0; i < 4; ++i)
          pn[m][n][i] = __builtin_amdgcn_exp2f(pn[m][n][i]);
#pragma unroll
      for (int k2 = 0; k2 < 2; ++k2) {
        const f16x2 c0 = pk2(pn[m][2 * k2][0], pn[m][2 * k2][1]);
        const f16x2 c1 = pk2(pn[m][2 * k2][2], pn[m][2 * k2][3]);
        const f16x2 c2 = pk2(pn[m][2 * k2 + 1][0], pn[m][2 * k2 + 1][1]);
        const f16x2 c3 = pk2(pn[m][2 * k2 + 1][2], pn[m][2 * k2 + 1][3]);
        pa[m][k2][0] = c0[0]; pa[m][k2][1] = c0[1];
        pa[m][k2][2] = c1[0]; pa[m][k2][3] = c1[1];
        pa[m][k2][4] = c2[0]; pa[m][k2][5] = c2[1];
        pa[m][k2][6] = c3[0]; pa[m][k2][7] = c3[1];
      }
    }
  };
  auto pv_tile = [&](int vbuf, f16x8 (&pa)[2][2]) {
#pragma unroll
    for (int k2 = 0; k2 < 2; ++k2) {
#pragma unroll
      for (int nf = 0; nf < 4; ++nf) {
        const int off = 16384 + vbuf * 4096 + (16 * nf + fr) * 64 +
                        (((k2 * 4 + fg) ^ kswz) * 8);
        const f16x8 vt = *(const f16x8*)&lds[off];
        oacc[0][nf] = MFMA_F16(vt, pa[0][k2], oacc[0][nf]);
        oacc[1][nf] = MFMA_F16(vt, pa[1][k2], oacc[1][nf]);
      }
      lacc[0] = MFMA_F16(ones, pa[0][k2], lacc[0]);
      lacc[1] = MFMA_F16(ones, pa[1][k2], lacc[1]);
    }
  };

  f32x4 pn[2][4];
  f16x8 pa[2][2][2];  // [ping][m][k2]

  stage_tile(0, 0);
  stage_tile(1, 1);
  stage_tile(2, 2);
  pipe_barrier_v4();
  qk_tile(0, pn);
  exp_pack(pn, pa[0]);

  for (int T = 0; T < 28; T += 4) {
#pragma unroll
    for (int s = 0; s < 4; ++s) {   // t = T+s ; t&3 == s
      stage_tile((s + 3) & 3, T + s + 3);
      __builtin_amdgcn_s_setprio(1);
      qk_tile((s + 1) & 3, pn);
      __builtin_amdgcn_s_setprio(0);
      __builtin_amdgcn_s_setprio(1);
      pv_tile(s & 3, pa[s & 1]);
      __builtin_amdgcn_s_setprio(0);
      exp_pack(pn, pa[(s + 1) & 1]);
      pipe_barrier_v4();
    }
  }
  {
    stage_tile(3, 31);
    __builtin_amdgcn_s_setprio(1); qk_tile(1, pn); __builtin_amdgcn_s_setprio(0);
    __builtin_amdgcn_s_setprio(1); pv_tile(0, pa[0]); __builtin_amdgcn_s_setprio(0);
    exp_pack(pn, pa[1]);
    pipe_barrier_v4();
    __builtin_amdgcn_s_setprio(1); qk_tile(2, pn); __builtin_amdgcn_s_setprio(0);
    __builtin_amdgcn_s_setprio(1); pv_tile(1, pa[1]); __builtin_amdgcn_s_setprio(0);
    exp_pack(pn, pa[0]);
    pipe_barrier_v0();
    __builtin_amdgcn_s_setprio(1); qk_tile(3, pn); __builtin_amdgcn_s_setprio(0);
    __builtin_amdgcn_s_setprio(1); pv_tile(2, pa[0]); __builtin_amdgcn_s_setprio(0);
    exp_pack(pn, pa[1]);
    pipe_barrier_v0();
    __builtin_amdgcn_s_setprio(1); pv_tile(3, pa[1]); __builtin_amdgcn_s_setprio(0);
  }

  float inv[2];
#pragma unroll
  for (int m = 0; m < 2; ++m) inv[m] = 1.0f / lacc[m][0];

  const int b = bh >> 4, h = bh & 15;
#pragma unroll
  for (int m = 0; m < 2; ++m) {
    const size_t orow = (size_t)(b * 2048 + q0 + 32 * w + 16 * m + fr);
#pragma unroll
    for (int nf = 0; nf < 4; ++nf) {
      f16x4 ov;
#pragma unroll
      for (int i = 0; i < 4; ++i) ov[i] = (_Float16)(oacc[m][nf][i] * inv[m]);
      *(f16x4*)&OB[orow * 1024 + h * 64 + 16 * nf + 4 * fg] = ov;
    }
  }
}

// ---------- GEMM: out = O @ Wproj + b, f32 out, BM=64 tiles, 3-buf pipe ------
__global__ __launch_bounds__(256) void gemm_proj_kernel(
    const _Float16* __restrict__ A, const _Float16* __restrict__ Bt,
    const float* __restrict__ bias, float* __restrict__ out) {
  __shared__ __attribute__((aligned(16))) _Float16 lg[18432];
  const int tid = threadIdx.x, lane = tid & 63, w = tid >> 6;
  const int wg = blockIdx.x;
  const int c = wg >> 3;                       // 0..63
  const int bxl = c & 7;                       // 0..7
  const int byl = (wg & 7) * 8 + (c >> 3);     // 0..63
  const int m0 = byl * 64, n0 = bxl * 128;
  const int wr = (w >> 1) * 32, wc = (w & 1) * 64;
  f32x4 acc[2][4] = {};
  const int srow = lane >> 2;
  const int scol = (((lane & 3) ^ ((lane >> 3) & 3)) * 8);
  const int fr = lane & 15, fg = lane >> 4;
  const int rswz = (fr >> 1) & 3;

  auto stageT = [&](int buf, int k0) {
    {
      const int rbase = 16 * w;
      gload_lds16(A + (size_t)(m0 + rbase + srow) * 1024 + k0 + scol,
                  &lg[buf * 6144 + rbase * 32]);
    }
#pragma unroll
    for (int j = 0; j < 2; ++j) {
      const int rbase = 32 * w + 16 * j;
      gload_lds16(Bt + (size_t)(n0 + rbase + srow) * 1024 + k0 + scol,
                  &lg[buf * 6144 + 2048 + rbase * 32]);
    }
  };
  auto mfma_step = [&](int ab) {
    f16x8 af[2], bfr[4];
#pragma unroll
    for (int m = 0; m < 2; ++m)
      af[m] = *(const f16x8*)&lg[ab + (wr + 16 * m + fr) * 32 + ((fg ^ rswz) * 8)];
#pragma unroll
    for (int n = 0; n < 4; ++n)
      bfr[n] = *(const f16x8*)&lg[ab + 2048 + (wc + 16 * n + fr) * 32 + ((fg ^ rswz) * 8)];
#pragma unroll
    for (int m = 0; m < 2; ++m)
#pragma unroll
      for (int n = 0; n < 4; ++n) acc[m][n] = MFMA_F16(af[m], bfr[n], acc[m][n]);
  };

  stageT(0, 0);
  stageT(1, 32);
  pipe_barrier_v3();
  for (int T = 0; T < 30; T += 3) {
#pragma unroll
    for (int s = 0; s < 3; ++s) {
      stageT((s + 2) % 3, (T + s + 2) * 32);
      mfma_step(s * 6144);
      pipe_barrier_v3();
    }
  }
  mfma_step(0);       // t=30
  pipe_barrier_v0();
  mfma_step(6144);    // t=31
  pipe_barrier_v0();

  const int fq = fg * 4;
#pragma unroll
  for (int n = 0; n < 4; ++n) {
    const int col = n0 + wc + 16 * n + fr;
    const float bv = bias[col];
#pragma unroll
    for (int m = 0; m < 2; ++m) {
#pragma unroll
      for (int i = 0; i < 4; ++i) {
        const int row = m0 + wr + 16 * m + fq + i;
        out[(size_t)row * 1024 + col] = acc[m][n][i] + bv;
      }
    }
  }
}

// ---------- launch ----------
extern "C" void kernel_launch(void* const* d_in, const int* in_sizes, int n_in,
                              void* d_out, int out_size, void* d_ws, size_t ws_size,
                              hipStream_t stream) {
  const float* x = (const float*)d_in[0];
  const float* Wqkv = (const float*)d_in[1];
  const float* bqkv = (const float*)d_in[2];
  const float* Wproj = (const float*)d_in[3];
  const float* bproj = (const float*)d_in[4];
  const float* sigma = (const float*)d_in[5];
  const float* gamma = (const float*)d_in[6];
  float* out = (float*)d_out;

  char* ws = (char*)d_ws;
  const size_t MB = 1024 * 1024;
  _Float16* XF  = (_Float16*)(ws + 0 * MB);   // 8MB  x (f16)
  _Float16* WQT = (_Float16*)(ws + 8 * MB);   // 6MB  Wqkv^T (dead after qkv GEMM)
  _Float16* WPT = (_Float16*)(ws + 14 * MB);  // 2MB  Wproj^T
  _Float16* QF  = (_Float16*)(ws + 16 * MB);  // 8MB  [B,H,N,D]
  _Float16* KF  = (_Float16*)(ws + 24 * MB);  // 8MB  [B,H,N,D]
  _Float16* VT  = (_Float16*)(ws + 32 * MB);  // 8MB  [B,H,D,N]
  _Float16* KT  = (_Float16*)(ws + 40 * MB);  // 8MB  (dead after gram)
  _Float16* OB  = (_Float16*)(ws + 40 * MB);  // 8MB  attn out (over KT)
  _Float16* GH  = (_Float16*)(ws + 8 * MB);   // 256KB Gram hi (over dead WQT)
  _Float16* GL  = (_Float16*)(ws + 8 * MB + 512 * 1024);  // 256KB Gram lo
  float*    GP  = (float*)(ws + 9 * MB);      // 4MB  Gram partials (f32, 256x4096)

  prep_kernel<<<8192, 256, 0, stream>>>(x, XF, Wqkv, WQT, Wproj, WPT);
  gemm_qkv_kernel<<<768, 256, 0, stream>>>(XF, WQT, bqkv, QF, KF, KT, VT);
  gram_partial_kernel<<<256, 256, 0, stream>>>(KT, GP);
  gram_reduce_kernel<<<128, 256, 0, stream>>>(GP, GH, GL);
  attn_kernel<<<512, 256, 0, stream>>>(QF, KF, VT, GH, GL, OB, sigma, gamma);
  gemm_proj_kernel<<<512, 256, 0, stream>>>(OB, WPT, bproj, out);
}